// Round 1
// baseline (388.337 us; speedup 1.0000x reference)
//
#include <hip/hip_runtime.h>
#include <cfloat>

#define DIM       2048
#define N_EXPERTS 64
#define BK        128   // K-chunk staged in LDS
#define TPW       8     // tokens per wave
#define WAVES     4     // waves per block
#define TPB       (TPW * WAVES)  // 32 tokens per block

__global__ __launch_bounds__(256, 2)
void topk_gate_kernel(const float* __restrict__ x,
                      const float* __restrict__ W,
                      const float* __restrict__ b,
                      float* __restrict__ out)
{
    __shared__ float xs[TPB * BK];  // [token][k], 32*128*4 = 16 KB

    const int tid     = threadIdx.x;
    const int lane    = tid & 63;
    const int wave    = tid >> 6;
    const int blk_tok = blockIdx.x * TPB;

    // lane == expert: this lane owns W row `lane`
    const float* wrow = W + (size_t)lane * DIM;
    const float  bias = b[lane];

    double accd[TPW];
    #pragma unroll
    for (int t = 0; t < TPW; ++t) accd[t] = 0.0;

    for (int k0 = 0; k0 < DIM; k0 += BK) {
        __syncthreads();  // previous chunk's reads complete before overwrite
        // Stage x[blk_tok..+32][k0..+BK] into LDS, coalesced.
        // 32*128/4 = 1024 float4s, 256 threads -> 4 each.
        #pragma unroll
        for (int r = 0; r < (TPB * BK / 4) / 256; ++r) {
            int idx = r * 256 + tid;     // float4 index
            int tok = idx >> 5;          // BK/4 = 32 float4 per token row
            int col = idx & 31;
            float4 v = *(const float4*)(x + (size_t)(blk_tok + tok) * DIM + k0 + col * 4);
            *(float4*)(xs + tok * BK + col * 4) = v;
        }
        __syncthreads();

        const float* xw = xs + (wave * TPW) * BK;

        #pragma unroll
        for (int kk = 0; kk < BK; kk += 32) {
            // fp32 sub-block accumulators, flushed to f64 every 32 k's
            float accf[TPW];
            #pragma unroll
            for (int t = 0; t < TPW; ++t) accf[t] = 0.f;

            #pragma unroll
            for (int k4 = 0; k4 < 32; k4 += 4) {
                float4 wv = *(const float4*)(wrow + k0 + kk + k4);
                #pragma unroll
                for (int t = 0; t < TPW; ++t) {
                    // wave-uniform address -> LDS broadcast, conflict-free
                    float4 xv = *(const float4*)(xw + t * BK + kk + k4);
                    accf[t] = fmaf(xv.x, wv.x, accf[t]);
                    accf[t] = fmaf(xv.y, wv.y, accf[t]);
                    accf[t] = fmaf(xv.z, wv.z, accf[t]);
                    accf[t] = fmaf(xv.w, wv.w, accf[t]);
                }
            }
            #pragma unroll
            for (int t = 0; t < TPW; ++t) accd[t] += (double)accf[t];
        }
    }

    // Epilogue: per token, top-2 across the 64 lanes (lane = expert)
    #pragma unroll
    for (int t = 0; t < TPW; ++t) {
        float s = (float)accd[t] + bias;

        // argmax with lower-index tie-break (matches lax.top_k stability)
        float v = s; int i = lane;
        #pragma unroll
        for (int off = 32; off > 0; off >>= 1) {
            float ov = __shfl_xor(v, off, 64);
            int   oi = __shfl_xor(i, off, 64);
            if (ov > v || (ov == v && oi < i)) { v = ov; i = oi; }
        }
        float m1 = v; int i1 = i;

        float s2 = (lane == i1) ? -FLT_MAX : s;
        v = s2; i = lane;
        #pragma unroll
        for (int off = 32; off > 0; off >>= 1) {
            float ov = __shfl_xor(v, off, 64);
            int   oi = __shfl_xor(i, off, 64);
            if (ov > v || (ov == v && oi < i)) { v = ov; i = oi; }
        }
        float m2 = v; int i2 = i;

        // weights: softmax masked to top-2, renormalized -> Z cancels
        float e   = __expf(m2 - m1);     // in (0, 1]
        float inv = 1.f / (1.f + e);
        float w1  = inv;
        float w2  = e * inv;

        float outv = (lane == i1) ? w1 : ((lane == i2) ? w2 : 0.f);
        out[(size_t)(blk_tok + wave * TPW + t) * N_EXPERTS + lane] = outv;
    }
}

extern "C" void kernel_launch(void* const* d_in, const int* in_sizes, int n_in,
                              void* d_out, int out_size, void* d_ws, size_t ws_size,
                              hipStream_t stream) {
    const float* x = (const float*)d_in[0];
    const float* W = (const float*)d_in[1];
    const float* b = (const float*)d_in[2];
    float* out = (float*)d_out;

    const int n_tokens = in_sizes[0] / DIM;   // 16384
    dim3 grid(n_tokens / TPB);                // 512 blocks
    dim3 block(256);
    topk_gate_kernel<<<grid, block, 0, stream>>>(x, W, b, out);
}